// Round 5
// baseline (794.784 us; speedup 1.0000x reference)
//
#include <hip/hip_runtime.h>
#include <math.h>

#define B_ 2
#define H_ 48
#define W_ 48
#define C_ 96
#define D_ 192
#define L_ 2304   // H_*W_
#define K_ 4
#define NS 32     // D_STATE
#define RK 6      // DT_RANK
#define CD 70     // RK + 2*NS

#define NC 16         // scan chunks
#define CL (L_/NC)    // 144 steps per chunk
#define NCH (B_*K_*D_)// 1536 chains

// workspace offsets (floats)
#define BDL (B_*D_*L_)                    // 884736
#define OFF_Z      0                      // z stored (b, l, d)
#define OFF_XPRE   (OFF_Z    + BDL)
#define OFF_XHW    (OFF_XPRE + BDL)
#define OFF_XWH    (OFF_XHW  + BDL)
#define OFF_DELTA  (OFF_XWH  + BDL)      // size B*K*D*L, layout (b,k,d,l)
#define OFF_BS     (OFF_DELTA+ B_*K_*D_*L_)  // (b,k,l,n)
#define OFF_CS     (OFF_BS   + B_*K_*L_*NS)
#define OFF_YS     (OFF_CS   + B_*K_*L_*NS)  // (b,k,l,d)
#define OFF_YF     (OFF_YS   + B_*K_*L_*D_)  // B*L*D

// lookback scratch inside YF region (dead until k5; k4f done before k5):
// Hbuf: 768 cells x 1024 floats = 786432 <= 884736
#define OFF_HB     OFF_YF
#define OFF_FLAG   (OFF_YF + 786432)      // 768 ints (as float slots)

// ---------------- K1: in_proj GEMM ------------------------------------------
// grid 576 = b(2) * ltile32(72) * es(4); es 0,1 -> xpre (b,d,pos); 2,3 -> z (b,l,d)
__global__ __launch_bounds__(256) void k1_inproj(const float* __restrict__ x,
        const float* __restrict__ w, float* __restrict__ ws) {
    __shared__ __align__(16) float Xs[24*128];   // [cq][l*4+sub], 32 l
    int blk = blockIdx.x;
    int b = blk / 288;
    int rem = blk % 288;
    int l0 = (rem >> 2) * 32;
    int es = rem & 3;
    int tid = threadIdx.x;
    const float4* xs4 = (const float4*)(x + (size_t)(b*L_ + l0)*C_);
    #pragma unroll
    for (int it = 0; it < 3; ++it) {
        int i4 = it*256 + tid;        // 768 float4 = 3072 floats
        float4 v = xs4[i4];
        int idx4 = i4*4;
        int p = idx4 / 96, c = idx4 % 96;   // c % 4 == 0
        *(float4*)&Xs[(c>>2)*128 + p*4] = v;
    }
    __syncthreads();
    int l = tid & 31, eg = tid >> 5;
    int pos = l0 + l;
    float acc[12];
    #pragma unroll
    for (int i = 0; i < 12; ++i) acc[i] = 0.f;
    const float4* wp[12];
    #pragma unroll
    for (int i = 0; i < 12; ++i) {
        int e = es*96 + eg*12 + i;
        wp[i] = (const float4*)(w + (size_t)e*96);
    }
    for (int q = 0; q < 24; ++q) {
        float4 xr = *(const float4*)&Xs[q*128 + l*4];
        #pragma unroll
        for (int i = 0; i < 12; ++i) {
            float4 wv = wp[i][q];
            acc[i] += xr.x*wv.x + xr.y*wv.y + xr.z*wv.z + xr.w*wv.w;
        }
    }
    if (es < 2) {
        float* xpre = ws + OFF_XPRE;
        #pragma unroll
        for (int i = 0; i < 12; ++i) {
            int e = es*96 + eg*12 + i;
            xpre[(size_t)(b*D_ + e)*L_ + pos] = acc[i];
        }
    } else {
        float* zp = ws + OFF_Z + (size_t)(b*L_ + pos)*D_ + (es-2)*96 + eg*12;
        #pragma unroll
        for (int q = 0; q < 3; ++q)
            *(float4*)&zp[q*4] = make_float4(acc[q*4], acc[q*4+1], acc[q*4+2], acc[q*4+3]);
    }
}

// ---------------- K2: depthwise 3x3 conv + SiLU, half-image blocks ----------
__global__ __launch_bounds__(256) void k2_conv(const float* __restrict__ cw,
        const float* __restrict__ cb, float* __restrict__ ws) {
    __shared__ float img[26*48];
    __shared__ float res[24*49];     // padded for transpose read
    int blk = blockIdx.x;            // 768 = bd*2 + half
    int bd = blk >> 1;
    int half = blk & 1;
    int d = bd % D_;
    int hh0 = half * 24;
    int tid = threadIdx.x;
    const float* xp = ws + OFF_XPRE + (size_t)bd*L_;
    for (int it = 0; it < 5; ++it) {
        int idx = it*256 + tid;
        if (idx < 26*48) {
            int gr = hh0 - 1 + idx/48;
            img[idx] = (gr >= 0 && gr < H_) ? xp[gr*48 + idx%48] : 0.f;
        }
    }
    float wr[9];
    #pragma unroll
    for (int j = 0; j < 9; ++j) wr[j] = cw[d*9 + j];
    float bias = cb[d];
    __syncthreads();
    float* hw = ws + OFF_XHW + (size_t)bd*L_ + hh0*48;
    for (int it = 0; it < 5; ++it) {
        int idx = it*256 + tid;
        if (idx < 24*48) {
            int r = idx/48, w0 = idx%48;
            float acc = bias;
            #pragma unroll
            for (int kh = 0; kh < 3; ++kh) {
                #pragma unroll
                for (int kw = 0; kw < 3; ++kw) {
                    int iw = w0 + kw - 1;
                    if (iw >= 0 && iw < W_)
                        acc = fmaf(img[(r+kh)*48 + iw], wr[kh*3 + kw], acc);
                }
            }
            float v = acc / (1.f + __expf(-acc));
            hw[idx] = v;
            res[r*49 + w0] = v;
        }
    }
    __syncthreads();
    float* wh = ws + OFF_XWH + (size_t)bd*L_;
    for (int it = 0; it < 5; ++it) {
        int idx = it*256 + tid;
        if (idx < 24*48) {
            int w0 = idx/24, r = idx%24;
            wh[w0*48 + hh0 + r] = res[r*49 + w0];
        }
    }
}

// ---------------- K3: x_proj matvec + dt_proj + softplus + B/C split --------
// grid 1152 = b(2) * k(4) * ltile16(144); also zeroes k4f lookback flags
__global__ __launch_bounds__(256) void k3_xproj(const float* __restrict__ xpw,
        const float* __restrict__ dtw, const float* __restrict__ dtb,
        float* __restrict__ ws) {
    __shared__ __align__(16) float Xs[48*64];    // [dq][l*4+sub], 16 l
    __shared__ float xd[CD*17];                  // [c][l], pad 17
    int blk = blockIdx.x;
    if (blk < 768 && threadIdx.x == 0)
        ((int*)(ws + OFF_FLAG))[blk] = 0;        // reset k4f flags each call
    int b = blk / 576;
    int rem = blk % 576;
    int k = rem / 144;
    int l0 = (rem % 144) * 16;
    int tid = threadIdx.x;
    const float* src = ws + ((k & 1) ? OFF_XWH : OFF_XHW);
    bool flip = (k >= 2);
    #pragma unroll
    for (int it = 0; it < 12; ++it) {
        int idx = it*256 + tid;
        int d = idx >> 4, l = idx & 15;
        int pos = flip ? (L_ - 1 - (l0 + l)) : (l0 + l);
        Xs[(d>>2)*64 + l*4 + (d&3)] = src[(size_t)(b*D_ + d)*L_ + pos];
    }
    __syncthreads();
    int l = tid & 15, cg = tid >> 4;    // 16 l x 16 cg
    {
        float acc[5] = {0.f, 0.f, 0.f, 0.f, 0.f};
        const float4* wp[5];
        #pragma unroll
        for (int i = 0; i < 5; ++i) {
            int c = cg + 16*i;
            if (c >= CD) c = 0;          // guard OOB; result masked on write
            wp[i] = (const float4*)(xpw + ((size_t)k*CD + c)*D_);
        }
        for (int q = 0; q < 48; ++q) {
            float4 xr = *(const float4*)&Xs[q*64 + l*4];
            #pragma unroll
            for (int i = 0; i < 5; ++i) {
                float4 wv = wp[i][q];
                acc[i] += xr.x*wv.x + xr.y*wv.y + xr.z*wv.z + xr.w*wv.w;
            }
        }
        #pragma unroll
        for (int i = 0; i < 5; ++i) {
            int c = cg + 16*i;
            if (c < CD) xd[c*17 + l] = acc[i];
        }
    }
    __syncthreads();
    {   // dt_proj + softplus -> deltas (b,k,d,l)
        float r[6];
        #pragma unroll
        for (int rr = 0; rr < 6; ++rr) r[rr] = xd[rr*17 + l];
        float* dout = ws + OFF_DELTA + (size_t)(b*K_ + k)*D_*L_;
        int dg = tid >> 4;
        for (int i = 0; i < 12; ++i) {
            int d = dg*12 + i;
            const float* wdt = dtw + ((size_t)k*D_ + d)*6;
            float acc = dtb[k*D_ + d];
            #pragma unroll
            for (int rr = 0; rr < 6; ++rr) acc = fmaf(r[rr], wdt[rr], acc);
            float sp = fmaxf(acc, 0.f) + log1pf(__expf(-fabsf(acc)));
            dout[(size_t)d*L_ + l0 + l] = sp;
        }
    }
    {   // Bs/Cs -> (b,k,l,n)
        float* Bsp = ws + OFF_BS + ((size_t)(b*K_ + k)*L_ + l0)*NS;
        float* Csp = ws + OFF_CS + ((size_t)(b*K_ + k)*L_ + l0)*NS;
        int n = tid & 31, lq = tid >> 5;
        #pragma unroll
        for (int j = 0; j < 2; ++j) {
            int ll = lq + 8*j;
            Bsp[(size_t)ll*NS + n] = xd[(RK + n)*17 + ll];
            Csp[(size_t)ll*NS + n] = xd[(RK + NS + n)*17 + ll];
        }
    }
}

// ---------------- K4f: fused chunked scan with decoupled lookback -----------
// grid 768 = c(16, MAJOR) x bk(8) x dg(6); 512 thr = 16 subwaves(d) x 32 n.
// All 768 blocks co-resident (8 waves, 19KB LDS, low VGPR -> >=3 blocks/CU,
// capacity 1024 slots >= 768), so the flag spin cannot deadlock.
__global__ __launch_bounds__(512) void k4f_scan(const float* __restrict__ Alogs,
        const float* __restrict__ Dsp, float* __restrict__ ws) {
    __shared__ float yld[CL*33];     // padded stride 33 -> conflict-free
    int blk = blockIdx.x;
    int c  = blk / 48;               // chunk index MAJOR -> in-order dispatch
    int bk = (blk % 48) / 6;
    int dg = blk % 6;
    int b = bk >> 2, k = bk & 3;
    int sw = threadIdx.x >> 5;
    int n  = threadIdx.x & 31;
    int dA = dg*32 + sw;
    int dB = dA + 16;
    float aA = -__expf(Alogs[((size_t)k*D_ + dA)*NS + n]);
    float aB = -__expf(Alogs[((size_t)k*D_ + dB)*NS + n]);
    float dcA = Dsp[k*D_ + dA];
    float dcB = Dsp[k*D_ + dB];
    const float* dpA = ws + OFF_DELTA + (size_t)(bk*D_ + dA)*L_ + c*CL;
    const float* dpB = dpA + 16*L_;
    const float* uA = ws + ((k & 1) ? OFF_XWH : OFF_XHW) + (size_t)(b*D_ + dA)*L_;
    const float* uB = uA + 16*L_;
    const float* Bsp = ws + OFF_BS + ((size_t)bk*L_ + c*CL)*NS;
    const float* Csp = ws + OFF_CS + ((size_t)bk*L_ + c*CL)*NS;
    bool flip = (k >= 2);

    // ---- phase 1: local chunk scan (P, hF in registers) ----
    float hA = 0.f, hB = 0.f, PA = 1.f, PB = 1.f;
    #pragma unroll 4
    for (int l = 0; l < CL; ++l) {
        int gl = c*CL + l;
        int gu = flip ? (L_ - 1 - gl) : gl;
        float dlA = dpA[l], dlB = dpB[l];
        float uAv = uA[gu], uBv = uB[gu];
        float bn = Bsp[l*NS + n];
        float eA = __expf(dlA * aA);
        float eB = __expf(dlB * aB);
        hA = fmaf(hA, eA, dlA*uAv*bn);
        hB = fmaf(hB, eB, dlB*uBv*bn);
        PA *= eA;
        PB *= eB;
    }

    // ---- lookback: get inclusive state of chunk c-1, publish own ----
    float* Hbuf = ws + OFF_HB;
    int* flg = (int*)(ws + OFF_FLAG);
    int cell = (bk*6 + dg)*NC + c;
    float h0A = 0.f, h0B = 0.f;
    if (c > 0) {
        if (threadIdx.x == 0) {
            while (__hip_atomic_load(&flg[cell-1], __ATOMIC_ACQUIRE,
                                     __HIP_MEMORY_SCOPE_AGENT) == 0) {
                __builtin_amdgcn_s_sleep(4);
            }
        }
        __syncthreads();
        h0A = __hip_atomic_load(&Hbuf[(size_t)(cell-1)*1024 + sw*32 + n],
                                __ATOMIC_RELAXED, __HIP_MEMORY_SCOPE_AGENT);
        h0B = __hip_atomic_load(&Hbuf[(size_t)(cell-1)*1024 + (sw+16)*32 + n],
                                __ATOMIC_RELAXED, __HIP_MEMORY_SCOPE_AGENT);
    }
    if (c < NC-1) {
        __hip_atomic_store(&Hbuf[(size_t)cell*1024 + sw*32 + n],
                           fmaf(h0A, PA, hA), __ATOMIC_RELAXED, __HIP_MEMORY_SCOPE_AGENT);
        __hip_atomic_store(&Hbuf[(size_t)cell*1024 + (sw+16)*32 + n],
                           fmaf(h0B, PB, hB), __ATOMIC_RELAXED, __HIP_MEMORY_SCOPE_AGENT);
        __threadfence();
        __syncthreads();
        if (threadIdx.x == 0)
            __hip_atomic_store(&flg[cell], 1, __ATOMIC_RELEASE,
                               __HIP_MEMORY_SCOPE_AGENT);
    }

    // ---- phase 2: replay with true h0; y-reduce; coalesced YS write ----
    hA = h0A; hB = h0B;
    int g = n >> 3;
    int off = ((g & 1) << 1) | (g >> 1);
    for (int lb = 0; lb < CL; lb += 4) {
        float yA[4], yB[4], uuA[4], uuB[4];
        #pragma unroll
        for (int j = 0; j < 4; ++j) {
            int l = lb + j;
            int gl = c*CL + l;
            int gu = flip ? (L_ - 1 - gl) : gl;
            float dlA = dpA[l], dlB = dpB[l];
            float uAv = uA[gu], uBv = uB[gu];
            float bn = Bsp[l*NS + n];
            float cn = Csp[l*NS + n];
            hA = fmaf(hA, __expf(dlA*aA), dlA*uAv*bn);
            hB = fmaf(hB, __expf(dlB*aB), dlB*uBv*bn);
            yA[j] = hA * cn; yB[j] = hB * cn;
            uuA[j] = uAv;    uuB[j] = uBv;
        }
        #pragma unroll
        for (int j = 0; j < 4; ++j) {
            yA[j] += __shfl_xor(yA[j], 16);
            yB[j] += __shfl_xor(yB[j], 16);
        }
        float zA0 = (n & 16) ? yA[1] : yA[0];
        float zA1 = (n & 16) ? yA[3] : yA[2];
        float zB0 = (n & 16) ? yB[1] : yB[0];
        float zB1 = (n & 16) ? yB[3] : yB[2];
        zA0 += __shfl_xor(zA0, 8); zA1 += __shfl_xor(zA1, 8);
        zB0 += __shfl_xor(zB0, 8); zB1 += __shfl_xor(zB1, 8);
        float wA = (n & 8) ? zA1 : zA0;
        float wB = (n & 8) ? zB1 : zB0;
        wA += __shfl_xor(wA, 4); wA += __shfl_xor(wA, 2); wA += __shfl_xor(wA, 1);
        wB += __shfl_xor(wB, 4); wB += __shfl_xor(wB, 2); wB += __shfl_xor(wB, 1);
        float uaA = (n & 16) ? uuA[1] : uuA[0];
        float ubA = (n & 16) ? uuA[3] : uuA[2];
        float usA = (n & 8) ? ubA : uaA;
        float uaB = (n & 16) ? uuB[1] : uuB[0];
        float ubB = (n & 16) ? uuB[3] : uuB[2];
        float usB = (n & 8) ? ubB : uaB;
        if ((n & 7) == 0) {
            yld[(lb + off)*33 + sw]      = fmaf(dcA, usA, wA);
            yld[(lb + off)*33 + sw + 16] = fmaf(dcB, usB, wB);
        }
    }
    __syncthreads();
    float* ysp = ws + OFF_YS + ((size_t)bk*L_ + c*CL)*D_ + dg*32;
    #pragma unroll
    for (int it = 0; it < 9; ++it) {
        int idx = it*512 + threadIdx.x;
        int l = idx >> 5, dd = idx & 31;
        ysp[(size_t)l*D_ + dd] = yld[l*33 + dd];
    }
}

// ---------------- K5: merge 4 directions + LayerNorm + SiLU(z) gate ---------
__global__ __launch_bounds__(192) void k5_combine(const float* __restrict__ lnw,
        const float* __restrict__ lnb, float* __restrict__ ws) {
    int bp = blockIdx.x;
    int b = bp / L_, pos = bp % L_;
    int d = threadIdx.x;
    int hh = pos / W_, w0 = pos % W_;
    int poswh = w0*H_ + hh;
    const float* ys = ws + OFF_YS + (size_t)b*K_*L_*D_;
    float y = ys[(size_t)(0*L_ + pos)*D_ + d]
            + ys[(size_t)(2*L_ + (L_ - 1 - pos))*D_ + d]
            + ys[(size_t)(1*L_ + poswh)*D_ + d]
            + ys[(size_t)(3*L_ + (L_ - 1 - poswh))*D_ + d];
    float s = y, ss = y*y;
    #pragma unroll
    for (int m = 32; m >= 1; m >>= 1) {
        s  += __shfl_xor(s, m);
        ss += __shfl_xor(ss, m);
    }
    __shared__ float red[2][4];
    int wv = threadIdx.x >> 6;
    if ((threadIdx.x & 63) == 0) { red[0][wv] = s; red[1][wv] = ss; }
    __syncthreads();
    float su = red[0][0] + red[0][1] + red[0][2];
    float sq = red[1][0] + red[1][1] + red[1][2];
    float mu  = su * (1.f/192.f);
    float var = sq * (1.f/192.f) - mu*mu;
    float rs  = rsqrtf(var + 1e-5f);
    float yn = (y - mu)*rs*lnw[d] + lnb[d];
    float zv = ws[OFF_Z + (size_t)(b*L_ + pos)*D_ + d];
    float sz = zv / (1.f + __expf(-zv));
    ws[OFF_YF + (size_t)(b*L_ + pos)*D_ + d] = yn * sz;
}

// ---------------- K6: out_proj GEMM + residual ------------------------------
// grid 576 = b(2) * ltile16(144) * es(2); LDS-staged coalesced epilogue
__global__ __launch_bounds__(256) void k6_outproj(const float* __restrict__ w,
        const float* __restrict__ xin, float* __restrict__ out,
        const float* __restrict__ ws) {
    __shared__ __align__(16) float Ys[48*64];    // [dq][l*4+sub], 16 l
    __shared__ float outT[16*49];
    int blk = blockIdx.x;
    int b = blk / 288;
    int rem = blk % 288;
    int l0 = (rem >> 1) * 16;
    int es = rem & 1;
    int tid = threadIdx.x;
    const float4* yf4 = (const float4*)(ws + OFF_YF + (size_t)(b*L_ + l0)*D_);
    #pragma unroll
    for (int it = 0; it < 3; ++it) {
        int i4 = it*256 + tid;        // 768 float4 = 3072 floats
        float4 v = yf4[i4];
        int idx4 = i4*4;
        int p = idx4 / 192, dd = idx4 % 192;
        *(float4*)&Ys[(dd>>2)*64 + p*4] = v;
    }
    __syncthreads();
    int l = tid & 15, cg = tid >> 4;
    float acc[3] = {0.f, 0.f, 0.f};
    const float4* wp[3];
    #pragma unroll
    for (int i = 0; i < 3; ++i) {
        int c = es*48 + cg*3 + i;
        wp[i] = (const float4*)(w + (size_t)c*D_);
    }
    for (int q = 0; q < 48; ++q) {
        float4 xr = *(const float4*)&Ys[q*64 + l*4];
        #pragma unroll
        for (int i = 0; i < 3; ++i) {
            float4 wv = wp[i][q];
            acc[i] += xr.x*wv.x + xr.y*wv.y + xr.z*wv.z + xr.w*wv.w;
        }
    }
    #pragma unroll
    for (int i = 0; i < 3; ++i) outT[l*49 + cg*3 + i] = acc[i];
    __syncthreads();
    #pragma unroll
    for (int it = 0; it < 3; ++it) {
        int idx = it*256 + tid;       // 768 outputs
        int p = idx / 48, cc = idx % 48;
        size_t o = (size_t)(b*L_ + l0 + p)*C_ + es*48 + cc;
        out[o] = xin[o] + outT[p*49 + cc];
    }
}

extern "C" void kernel_launch(void* const* d_in, const int* in_sizes, int n_in,
                              void* d_out, int out_size, void* d_ws, size_t ws_size,
                              hipStream_t stream) {
    const float* x        = (const float*)d_in[0];
    const float* in_proj  = (const float*)d_in[1];
    const float* conv_w   = (const float*)d_in[2];
    const float* conv_b   = (const float*)d_in[3];
    const float* x_proj_w = (const float*)d_in[4];
    const float* dt_w     = (const float*)d_in[5];
    const float* dt_b     = (const float*)d_in[6];
    const float* A_logs   = (const float*)d_in[7];
    const float* Ds       = (const float*)d_in[8];
    const float* ln_w     = (const float*)d_in[9];
    const float* ln_b     = (const float*)d_in[10];
    const float* out_w    = (const float*)d_in[11];
    float* out = (float*)d_out;
    float* ws  = (float*)d_ws;

    k1_inproj <<<576,  256, 0, stream>>>(x, in_proj, ws);
    k2_conv   <<<768,  256, 0, stream>>>(conv_w, conv_b, ws);
    k3_xproj  <<<1152, 256, 0, stream>>>(x_proj_w, dt_w, dt_b, ws);
    k4f_scan  <<<768,  512, 0, stream>>>(A_logs, Ds, ws);
    k5_combine<<<B_*L_,192, 0, stream>>>(ln_w, ln_b, ws);
    k6_outproj<<<576,  256, 0, stream>>>(out_w, x, out, ws);
}

// Round 6
// 289.549 us; speedup vs baseline: 2.7449x; 2.7449x over previous
//
#include <hip/hip_runtime.h>
#include <math.h>

#define B_ 2
#define H_ 48
#define W_ 48
#define C_ 96
#define D_ 192
#define L_ 2304   // H_*W_
#define K_ 4
#define NS 32     // D_STATE
#define RK 6      // DT_RANK
#define CD 70     // RK + 2*NS

#define NC 16         // scan chunks
#define CL (L_/NC)    // 144 steps per chunk
#define NCH (B_*K_*D_)// 1536 chains
#define LOG2E 1.44269504088896f

__device__ __forceinline__ float fexp2(float x) {
#if __has_builtin(__builtin_amdgcn_exp2f)
    return __builtin_amdgcn_exp2f(x);
#else
    return __expf(x * 0.69314718055994531f);
#endif
}

// workspace offsets (floats)
#define BDL (B_*D_*L_)                    // 884736
#define OFF_Z      0                      // z stored (b, l, d)
#define OFF_XPRE   (OFF_Z    + BDL)
#define OFF_XHW    (OFF_XPRE + BDL)
#define OFF_XWH    (OFF_XHW  + BDL)
#define OFF_DELTA  (OFF_XWH  + BDL)      // size B*K*D*L, layout (b,k,d,l)
#define OFF_BS     (OFF_DELTA+ B_*K_*D_*L_)  // (b,k,l,n)
#define OFF_CS     (OFF_BS   + B_*K_*L_*NS)
#define OFF_YS     (OFF_CS   + B_*K_*L_*NS)  // (b,k,l,d)
#define OFF_YF     (OFF_YS   + B_*K_*L_*D_)  // B*L*D

// H0 scratch: NCH*NC*NS = 786432 <= YF region (884736); consumed by k4c
// before k5 writes YF.
#define OFF_H0     OFF_YF

// ---------------- K1: in_proj GEMM ------------------------------------------
// grid 576 = b(2) * ltile32(72) * es(4); es 0,1 -> xpre (b,d,pos); 2,3 -> z (b,l,d)
__global__ __launch_bounds__(256) void k1_inproj(const float* __restrict__ x,
        const float* __restrict__ w, float* __restrict__ ws) {
    __shared__ __align__(16) float Xs[24*128];   // [cq][l*4+sub], 32 l
    int blk = blockIdx.x;
    int b = blk / 288;
    int rem = blk % 288;
    int l0 = (rem >> 2) * 32;
    int es = rem & 3;
    int tid = threadIdx.x;
    const float4* xs4 = (const float4*)(x + (size_t)(b*L_ + l0)*C_);
    #pragma unroll
    for (int it = 0; it < 3; ++it) {
        int i4 = it*256 + tid;        // 768 float4 = 3072 floats
        float4 v = xs4[i4];
        int idx4 = i4*4;
        int p = idx4 / 96, c = idx4 % 96;   // c % 4 == 0
        *(float4*)&Xs[(c>>2)*128 + p*4] = v;
    }
    __syncthreads();
    int l = tid & 31, eg = tid >> 5;
    int pos = l0 + l;
    float acc[12];
    #pragma unroll
    for (int i = 0; i < 12; ++i) acc[i] = 0.f;
    const float4* wp[12];
    #pragma unroll
    for (int i = 0; i < 12; ++i) {
        int e = es*96 + eg*12 + i;
        wp[i] = (const float4*)(w + (size_t)e*96);
    }
    for (int q = 0; q < 24; ++q) {
        float4 xr = *(const float4*)&Xs[q*128 + l*4];
        #pragma unroll
        for (int i = 0; i < 12; ++i) {
            float4 wv = wp[i][q];
            acc[i] += xr.x*wv.x + xr.y*wv.y + xr.z*wv.z + xr.w*wv.w;
        }
    }
    if (es < 2) {
        float* xpre = ws + OFF_XPRE;
        #pragma unroll
        for (int i = 0; i < 12; ++i) {
            int e = es*96 + eg*12 + i;
            xpre[(size_t)(b*D_ + e)*L_ + pos] = acc[i];
        }
    } else {
        float* zp = ws + OFF_Z + (size_t)(b*L_ + pos)*D_ + (es-2)*96 + eg*12;
        #pragma unroll
        for (int q = 0; q < 3; ++q)
            *(float4*)&zp[q*4] = make_float4(acc[q*4], acc[q*4+1], acc[q*4+2], acc[q*4+3]);
    }
}

// ---------------- K2: depthwise 3x3 conv + SiLU, half-image blocks ----------
__global__ __launch_bounds__(256) void k2_conv(const float* __restrict__ cw,
        const float* __restrict__ cb, float* __restrict__ ws) {
    __shared__ float img[26*48];
    __shared__ float res[24*49];     // padded for transpose read
    int blk = blockIdx.x;            // 768 = bd*2 + half
    int bd = blk >> 1;
    int half = blk & 1;
    int d = bd % D_;
    int hh0 = half * 24;
    int tid = threadIdx.x;
    const float* xp = ws + OFF_XPRE + (size_t)bd*L_;
    for (int it = 0; it < 5; ++it) {
        int idx = it*256 + tid;
        if (idx < 26*48) {
            int gr = hh0 - 1 + idx/48;
            img[idx] = (gr >= 0 && gr < H_) ? xp[gr*48 + idx%48] : 0.f;
        }
    }
    float wr[9];
    #pragma unroll
    for (int j = 0; j < 9; ++j) wr[j] = cw[d*9 + j];
    float bias = cb[d];
    __syncthreads();
    float* hw = ws + OFF_XHW + (size_t)bd*L_ + hh0*48;
    for (int it = 0; it < 5; ++it) {
        int idx = it*256 + tid;
        if (idx < 24*48) {
            int r = idx/48, w0 = idx%48;
            float acc = bias;
            #pragma unroll
            for (int kh = 0; kh < 3; ++kh) {
                #pragma unroll
                for (int kw = 0; kw < 3; ++kw) {
                    int iw = w0 + kw - 1;
                    if (iw >= 0 && iw < W_)
                        acc = fmaf(img[(r+kh)*48 + iw], wr[kh*3 + kw], acc);
                }
            }
            float v = acc / (1.f + __expf(-acc));
            hw[idx] = v;
            res[r*49 + w0] = v;
        }
    }
    __syncthreads();
    float* wh = ws + OFF_XWH + (size_t)bd*L_;
    for (int it = 0; it < 5; ++it) {
        int idx = it*256 + tid;
        if (idx < 24*48) {
            int w0 = idx/24, r = idx%24;
            wh[w0*48 + hh0 + r] = res[r*49 + w0];
        }
    }
}

// ---------------- K3: x_proj matvec + dt_proj + softplus + B/C split --------
// grid 1152 = b(2) * k(4) * ltile16(144)
__global__ __launch_bounds__(256) void k3_xproj(const float* __restrict__ xpw,
        const float* __restrict__ dtw, const float* __restrict__ dtb,
        float* __restrict__ ws) {
    __shared__ __align__(16) float Xs[48*64];    // [dq][l*4+sub], 16 l
    __shared__ float xd[CD*17];                  // [c][l], pad 17
    int blk = blockIdx.x;
    int b = blk / 576;
    int rem = blk % 576;
    int k = rem / 144;
    int l0 = (rem % 144) * 16;
    int tid = threadIdx.x;
    const float* src = ws + ((k & 1) ? OFF_XWH : OFF_XHW);
    bool flip = (k >= 2);
    #pragma unroll
    for (int it = 0; it < 12; ++it) {
        int idx = it*256 + tid;
        int d = idx >> 4, l = idx & 15;
        int pos = flip ? (L_ - 1 - (l0 + l)) : (l0 + l);
        Xs[(d>>2)*64 + l*4 + (d&3)] = src[(size_t)(b*D_ + d)*L_ + pos];
    }
    __syncthreads();
    int l = tid & 15, cg = tid >> 4;    // 16 l x 16 cg
    {
        float acc[5] = {0.f, 0.f, 0.f, 0.f, 0.f};
        const float4* wp[5];
        #pragma unroll
        for (int i = 0; i < 5; ++i) {
            int c = cg + 16*i;
            if (c >= CD) c = 0;          // guard OOB; result masked on write
            wp[i] = (const float4*)(xpw + ((size_t)k*CD + c)*D_);
        }
        for (int q = 0; q < 48; ++q) {
            float4 xr = *(const float4*)&Xs[q*64 + l*4];
            #pragma unroll
            for (int i = 0; i < 5; ++i) {
                float4 wv = wp[i][q];
                acc[i] += xr.x*wv.x + xr.y*wv.y + xr.z*wv.z + xr.w*wv.w;
            }
        }
        #pragma unroll
        for (int i = 0; i < 5; ++i) {
            int c = cg + 16*i;
            if (c < CD) xd[c*17 + l] = acc[i];
        }
    }
    __syncthreads();
    {   // dt_proj + softplus -> deltas (b,k,d,l)
        float r[6];
        #pragma unroll
        for (int rr = 0; rr < 6; ++rr) r[rr] = xd[rr*17 + l];
        float* dout = ws + OFF_DELTA + (size_t)(b*K_ + k)*D_*L_;
        int dg = tid >> 4;
        for (int i = 0; i < 12; ++i) {
            int d = dg*12 + i;
            const float* wdt = dtw + ((size_t)k*D_ + d)*6;
            float acc = dtb[k*D_ + d];
            #pragma unroll
            for (int rr = 0; rr < 6; ++rr) acc = fmaf(r[rr], wdt[rr], acc);
            float sp = fmaxf(acc, 0.f) + log1pf(__expf(-fabsf(acc)));
            dout[(size_t)d*L_ + l0 + l] = sp;
        }
    }
    {   // Bs/Cs -> (b,k,l,n)
        float* Bsp = ws + OFF_BS + ((size_t)(b*K_ + k)*L_ + l0)*NS;
        float* Csp = ws + OFF_CS + ((size_t)(b*K_ + k)*L_ + l0)*NS;
        int n = tid & 31, lq = tid >> 5;
        #pragma unroll
        for (int j = 0; j < 2; ++j) {
            int ll = lq + 8*j;
            Bsp[(size_t)ll*NS + n] = xd[(RK + n)*17 + ll];
            Csp[(size_t)ll*NS + n] = xd[(RK + NS + n)*17 + ll];
        }
    }
}

// ---------------- K4a: local chunk scan + in-LDS combine -> H0 --------------
// grid 1536 = bk(8) * d(192); 512 thr = 16 chunks x 32 states; 1 chain/lane
__global__ __launch_bounds__(512) void k4a_local(const float* __restrict__ Alogs,
        float* __restrict__ ws) {
    __shared__ float Pl[NC][NS];
    __shared__ float Hl[NC][NS];
    int blk = blockIdx.x;
    int d = blk % D_;
    int bk = blk / D_;
    int b = bk >> 2, k = bk & 3;
    int c = threadIdx.x >> 5;
    int n = threadIdx.x & 31;
    float a2 = -__expf(Alogs[((size_t)k*D_ + d)*NS + n]) * LOG2E;
    const float* dptr = ws + OFF_DELTA + (size_t)(bk*D_ + d)*L_ + c*CL;
    const float* ubase = ws + ((k & 1) ? OFF_XWH : OFF_XHW) + (size_t)(b*D_ + d)*L_;
    const float* Bsp = ws + OFF_BS + ((size_t)bk*L_ + c*CL)*NS;
    bool flip = (k >= 2);
    float h = 0.f, sd = 0.f;
    for (int lb = 0; lb < CL; lb += 4) {
        float4 d4 = *(const float4*)(dptr + lb);
        float4 t4;
        if (!flip) {
            t4 = *(const float4*)(ubase + c*CL + lb);
        } else {
            float4 r = *(const float4*)(ubase + (L_ - 4) - (c*CL + lb));
            t4 = make_float4(r.w, r.z, r.y, r.x);
        }
        float dl[4] = {d4.x, d4.y, d4.z, d4.w};
        float uu[4] = {t4.x, t4.y, t4.z, t4.w};
        #pragma unroll
        for (int j = 0; j < 4; ++j) {
            float bn = Bsp[(lb + j)*NS + n];
            float e = fexp2(dl[j]*a2);
            h = fmaf(h, e, dl[j]*uu[j]*bn);
            sd += dl[j];
        }
    }
    Pl[c][n] = fexp2(a2*sd);   // product of dA over chunk == exp(a * sum delta)
    Hl[c][n] = h;
    __syncthreads();
    if (threadIdx.x < NS) {    // serial combine over chunks; n = threadIdx.x
        float hh = 0.f;
        #pragma unroll
        for (int cc = 0; cc < NC; ++cc) {
            float p  = Pl[cc][n];
            float hf = Hl[cc][n];
            Pl[cc][n] = hh;    // overwrite with h0 for chunk cc
            hh = fmaf(hh, p, hf);
        }
    }
    __syncthreads();
    // coalesced H0 write: layout (chain, c, n), linear in tid
    ws[OFF_H0 + (size_t)(bk*D_ + d)*NC*NS + threadIdx.x] = Pl[c][n];
}

// ---------------- K4c: replay from true h0; y-reduce; coalesced YS write ----
// grid 1536 = bk(8) * c(16) * dg(12); 512 thr = 16 subwaves(d) x 32 states
__global__ __launch_bounds__(512) void k4c_scan(const float* __restrict__ Alogs,
        const float* __restrict__ Dsp, float* __restrict__ ws) {
    __shared__ float yld[CL*17];     // [l][d], stride 17 -> conflict-free
    int blk = blockIdx.x;
    int dg = blk % 12;
    int c  = (blk / 12) % NC;
    int bk = blk / (12*NC);
    int b = bk >> 2, k = bk & 3;
    int sw = threadIdx.x >> 5;
    int n  = threadIdx.x & 31;
    int d = dg*16 + sw;
    float a2 = -__expf(Alogs[((size_t)k*D_ + d)*NS + n]) * LOG2E;
    float dc = Dsp[k*D_ + d];
    const float* dptr = ws + OFF_DELTA + (size_t)(bk*D_ + d)*L_ + c*CL;
    const float* ubase = ws + ((k & 1) ? OFF_XWH : OFF_XHW) + (size_t)(b*D_ + d)*L_;
    const float* Bsp = ws + OFF_BS + ((size_t)bk*L_ + c*CL)*NS;
    const float* Csp = ws + OFF_CS + ((size_t)bk*L_ + c*CL)*NS;
    bool flip = (k >= 2);
    float h = ws[OFF_H0 + (size_t)(bk*D_ + d)*NC*NS + c*NS + n];
    int g = n >> 3;
    int off = ((g & 1) << 1) | (g >> 1);   // lane-group -> l-offset [0,2,1,3]
    for (int lb = 0; lb < CL; lb += 4) {
        float4 d4 = *(const float4*)(dptr + lb);
        float4 t4;
        if (!flip) {
            t4 = *(const float4*)(ubase + c*CL + lb);
        } else {
            float4 r = *(const float4*)(ubase + (L_ - 4) - (c*CL + lb));
            t4 = make_float4(r.w, r.z, r.y, r.x);
        }
        float dl[4] = {d4.x, d4.y, d4.z, d4.w};
        float uu[4] = {t4.x, t4.y, t4.z, t4.w};
        float y[4];
        #pragma unroll
        for (int j = 0; j < 4; ++j) {
            float bn = Bsp[(lb + j)*NS + n];
            float cn = Csp[(lb + j)*NS + n];
            float e = fexp2(dl[j]*a2);
            h = fmaf(h, e, dl[j]*uu[j]*bn);
            y[j] = h * cn;
        }
        // shared butterfly: 4 values reduced across 32 lanes
        #pragma unroll
        for (int j = 0; j < 4; ++j) y[j] += __shfl_xor(y[j], 16);
        float z0 = (n & 16) ? y[1] : y[0];
        float z1 = (n & 16) ? y[3] : y[2];
        z0 += __shfl_xor(z0, 8);
        z1 += __shfl_xor(z1, 8);
        float wv = (n & 8) ? z1 : z0;
        wv += __shfl_xor(wv, 4);
        wv += __shfl_xor(wv, 2);
        wv += __shfl_xor(wv, 1);
        float ua = (n & 16) ? uu[1] : uu[0];
        float ub = (n & 16) ? uu[3] : uu[2];
        float us = (n & 8) ? ub : ua;
        if ((n & 7) == 0) yld[(lb + off)*17 + sw] = fmaf(dc, us, wv);
    }
    __syncthreads();
    float* ysp = ws + OFF_YS + ((size_t)bk*L_ + c*CL)*D_ + dg*16;
    for (int it = 0; it < 5; ++it) {
        int idx = it*512 + threadIdx.x;
        if (idx < CL*16) {
            int l = idx >> 4, dd = idx & 15;
            ysp[(size_t)l*D_ + dd] = yld[l*17 + dd];
        }
    }
}

// ---------------- K5: merge 4 directions + LayerNorm + SiLU(z) gate ---------
__global__ __launch_bounds__(192) void k5_combine(const float* __restrict__ lnw,
        const float* __restrict__ lnb, float* __restrict__ ws) {
    int bp = blockIdx.x;
    int b = bp / L_, pos = bp % L_;
    int d = threadIdx.x;
    int hh = pos / W_, w0 = pos % W_;
    int poswh = w0*H_ + hh;
    const float* ys = ws + OFF_YS + (size_t)b*K_*L_*D_;
    float y = ys[(size_t)(0*L_ + pos)*D_ + d]
            + ys[(size_t)(2*L_ + (L_ - 1 - pos))*D_ + d]
            + ys[(size_t)(1*L_ + poswh)*D_ + d]
            + ys[(size_t)(3*L_ + (L_ - 1 - poswh))*D_ + d];
    float s = y, ss = y*y;
    #pragma unroll
    for (int m = 32; m >= 1; m >>= 1) {
        s  += __shfl_xor(s, m);
        ss += __shfl_xor(ss, m);
    }
    __shared__ float red[2][4];
    int wv = threadIdx.x >> 6;
    if ((threadIdx.x & 63) == 0) { red[0][wv] = s; red[1][wv] = ss; }
    __syncthreads();
    float su = red[0][0] + red[0][1] + red[0][2];
    float sq = red[1][0] + red[1][1] + red[1][2];
    float mu  = su * (1.f/192.f);
    float var = sq * (1.f/192.f) - mu*mu;
    float rs  = rsqrtf(var + 1e-5f);
    float yn = (y - mu)*rs*lnw[d] + lnb[d];
    float zv = ws[OFF_Z + (size_t)(b*L_ + pos)*D_ + d];
    float sz = zv / (1.f + __expf(-zv));
    ws[OFF_YF + (size_t)(b*L_ + pos)*D_ + d] = yn * sz;
}

// ---------------- K6: out_proj GEMM + residual ------------------------------
// grid 576 = b(2) * ltile16(144) * es(2); LDS-staged coalesced epilogue
__global__ __launch_bounds__(256) void k6_outproj(const float* __restrict__ w,
        const float* __restrict__ xin, float* __restrict__ out,
        const float* __restrict__ ws) {
    __shared__ __align__(16) float Ys[48*64];    // [dq][l*4+sub], 16 l
    __shared__ float outT[16*49];
    int blk = blockIdx.x;
    int b = blk / 288;
    int rem = blk % 288;
    int l0 = (rem >> 1) * 16;
    int es = rem & 1;
    int tid = threadIdx.x;
    const float4* yf4 = (const float4*)(ws + OFF_YF + (size_t)(b*L_ + l0)*D_);
    #pragma unroll
    for (int it = 0; it < 3; ++it) {
        int i4 = it*256 + tid;        // 768 float4 = 3072 floats
        float4 v = yf4[i4];
        int idx4 = i4*4;
        int p = idx4 / 192, dd = idx4 % 192;
        *(float4*)&Ys[(dd>>2)*64 + p*4] = v;
    }
    __syncthreads();
    int l = tid & 15, cg = tid >> 4;
    float acc[3] = {0.f, 0.f, 0.f};
    const float4* wp[3];
    #pragma unroll
    for (int i = 0; i < 3; ++i) {
        int c = es*48 + cg*3 + i;
        wp[i] = (const float4*)(w + (size_t)c*D_);
    }
    for (int q = 0; q < 48; ++q) {
        float4 xr = *(const float4*)&Ys[q*64 + l*4];
        #pragma unroll
        for (int i = 0; i < 3; ++i) {
            float4 wv = wp[i][q];
            acc[i] += xr.x*wv.x + xr.y*wv.y + xr.z*wv.z + xr.w*wv.w;
        }
    }
    #pragma unroll
    for (int i = 0; i < 3; ++i) outT[l*49 + cg*3 + i] = acc[i];
    __syncthreads();
    #pragma unroll
    for (int it = 0; it < 3; ++it) {
        int idx = it*256 + tid;       // 768 outputs
        int p = idx / 48, cc = idx % 48;
        size_t o = (size_t)(b*L_ + l0 + p)*C_ + es*48 + cc;
        out[o] = xin[o] + outT[p*49 + cc];
    }
}

extern "C" void kernel_launch(void* const* d_in, const int* in_sizes, int n_in,
                              void* d_out, int out_size, void* d_ws, size_t ws_size,
                              hipStream_t stream) {
    const float* x        = (const float*)d_in[0];
    const float* in_proj  = (const float*)d_in[1];
    const float* conv_w   = (const float*)d_in[2];
    const float* conv_b   = (const float*)d_in[3];
    const float* x_proj_w = (const float*)d_in[4];
    const float* dt_w     = (const float*)d_in[5];
    const float* dt_b     = (const float*)d_in[6];
    const float* A_logs   = (const float*)d_in[7];
    const float* Ds       = (const float*)d_in[8];
    const float* ln_w     = (const float*)d_in[9];
    const float* ln_b     = (const float*)d_in[10];
    const float* out_w    = (const float*)d_in[11];
    float* out = (float*)d_out;
    float* ws  = (float*)d_ws;

    k1_inproj <<<576,  256, 0, stream>>>(x, in_proj, ws);
    k2_conv   <<<768,  256, 0, stream>>>(conv_w, conv_b, ws);
    k3_xproj  <<<1152, 256, 0, stream>>>(x_proj_w, dt_w, dt_b, ws);
    k4a_local <<<NCH,  512, 0, stream>>>(A_logs, ws);
    k4c_scan  <<<1536, 512, 0, stream>>>(A_logs, Ds, ws);
    k5_combine<<<B_*L_,192, 0, stream>>>(ln_w, ln_b, ws);
    k6_outproj<<<576,  256, 0, stream>>>(out_w, x, out, ws);
}